// Round 9
// baseline (665.266 us; speedup 1.0000x reference)
//
#include <hip/hip_runtime.h>

// B=64, T=64 -> GEMM M=4096, N=2048, K=2048 ; tdBN ; LIF scan. Full f64
// results (r1/r4/r6/r7/r8: absmax == 0.0). Round 9: cross-block barrier
// overlap. r8 was pipe-busy 83% with 2 blocks/CU whose waves drain the same
// per-iteration barrier in lockstep. Retile to 64x128 blocks (4 waves x
// 32x64), BK=16, grid 1024 -> 4 independent blocks/CU (m114: different
// blocks' barriers are uncorrelated -> MFMA pipe stays fed during drains).
// LDS 26 KB/block, padded k-row strides (68/136 words) -> conflict-free
// fragment reads. Self-calibrating f64-MFMA layout probe kept verbatim.

typedef double double4v __attribute__((ext_vector_type(4)));

#define KDIM 2048
#define NDIM 2048
#define BKt  16
#define LRA  68    // A k-row stride in words (64 + 4 pad)
#define LRB  136   // B k-row stride in words (128 + 8 pad)

__global__ __launch_bounds__(256, 4) void gemm_f64_mfma4(
    const float* __restrict__ X,   // (4096, 2048)
    const float* __restrict__ W,   // (2048, 2048)
    const float* __restrict__ bias,
    double* __restrict__ H)        // (4096, 2048)
{
    constexpr int NT = KDIM / BKt;           // 128
    __shared__ float As[2][BKt][LRA];        // 8.5 KB
    __shared__ float Bs[2][BKt][LRB];        // 17 KB

    const int tid  = threadIdx.x;
    const int lane = tid & 63;
    const int wid  = tid >> 6;
    const int lf = lane & 15, lq = lane >> 4;
    const int bm = blockIdx.x * 64, bn = blockIdx.y * 128;
    const int wrow = wid >> 1, wcol = wid & 1;   // wave -> 32x64 subtile

    // ---------------- layout self-calibration probe (r7-verified) ----------------
    double4v pd = (double4v){0.0, 0.0, 0.0, 0.0};
    pd = __builtin_amdgcn_mfma_f64_16x16x4f64(
        (double)(lane + 1), (double)((lane + 1) * (lane + 1)), pd, 0, 0, 0);
    int winner = -1;
    #pragma unroll
    for (int h = 0; h < 16; ++h) {
        const int c1 = h & 1, c2 = (h >> 1) & 1, cd = h >> 2;
        bool ok = true;
        #pragma unroll
        for (int v = 0; v < 4; ++v) {
            const int r16 = (cd == 0) ? 4 * lq + v : (cd == 1) ? lf
                          : (cd == 2) ? lq + 4 * v : lf;
            const int c16 = (cd == 0) ? lf : (cd == 1) ? 4 * lq + v
                          : (cd == 2) ? lf : lq + 4 * v;
            double s = 0.0;
            #pragma unroll
            for (int k = 0; k < 4; ++k) {
                const int i1 = c1 ? (r16 + 16 * k) : (4 * r16 + k);
                const int i2 = c2 ? (c16 + 16 * k) : (4 * c16 + k);
                s += (double)(i1 + 1) * (double)((i2 + 1) * (i2 + 1));
            }
            ok = ok && (pd[v] == s);
        }
        if (__ballot(ok) == ~0ull && winner < 0) winner = h;
    }
    if (winner < 0) winner = 0;
    const int selA = winner & 1, selB = (winner >> 1) & 1, selD = winner >> 2;

    const int rlA = selA ? lf : (lane >> 2);
    const int klA = selA ? lq : (lane & 3);
    const int rlB = selB ? lf : (lane >> 2);
    const int klB = selB ? lq : (lane & 3);
    // A perm: pos(r)= (r&15)*4 + (r>>4); lane's rows {wrow*32+16t+rlA, t=0,1}
    //   -> contiguous pair at rlA*4 + wrow*2  (ds_read_b64)
    const int baseA = klA * LRA + rlA * 4 + wrow * 2;
    // B perm: pos(c)= (c>>6)*64 + (c&15)*4 + ((c>>4)&3); lane's cols
    //   {wcol*64+16t+rlB, t=0..3} -> contiguous 4 at wcol*64 + rlB*4 (b128)
    const int baseB = klB * LRB + wcol * 64 + rlB * 4;

    // ---------------- staging ----------------
    const int aRow = tid >> 2;            // 0..63
    const int aKof = (tid & 3) << 2;      // 0,4,8,12
    const int bRow = tid >> 1;            // 0..127
    const int bKof = (tid & 1) << 3;      // 0,8
    const float* xa = X + (size_t)(bm + aRow) * KDIM + aKof;
    const float* wa = W + (size_t)(bn + bRow) * KDIM + bKof;
    const int posA = (aRow & 15) * 4 + (aRow >> 4);
    const int posB = (bRow >> 6) * 64 + (bRow & 15) * 4 + ((bRow >> 4) & 3);

#define STAGE(buf, A0, B0, B1) do { \
    As[buf][aKof + 0][posA] = A0.x; As[buf][aKof + 1][posA] = A0.y; \
    As[buf][aKof + 2][posA] = A0.z; As[buf][aKof + 3][posA] = A0.w; \
    Bs[buf][bKof + 0][posB] = B0.x; Bs[buf][bKof + 1][posB] = B0.y; \
    Bs[buf][bKof + 2][posB] = B0.z; Bs[buf][bKof + 3][posB] = B0.w; \
    Bs[buf][bKof + 4][posB] = B1.x; Bs[buf][bKof + 5][posB] = B1.y; \
    Bs[buf][bKof + 6][posB] = B1.z; Bs[buf][bKof + 7][posB] = B1.w; } while (0)

    double4v acc[2][4];
    #pragma unroll
    for (int t = 0; t < 2; ++t)
        #pragma unroll
        for (int u = 0; u < 4; ++u)
            acc[t][u] = (double4v){0.0, 0.0, 0.0, 0.0};

    {   // prologue: stage k-tile 0
        float4 a0 = *(const float4*)(xa);
        float4 b0 = *(const float4*)(wa);
        float4 b1 = *(const float4*)(wa + 4);
        STAGE(0, a0, b0, b1);
    }
    __syncthreads();

    int cur = 0;
    for (int t = 0; t < NT; ++t) {
        const bool more = (t + 1) < NT;
        float4 pa0, pb0, pb1;
        if (more) {
            const int k0 = (t + 1) * BKt;
            pa0 = *(const float4*)(xa + k0);
            pb0 = *(const float4*)(wa + k0);
            pb1 = *(const float4*)(wa + k0 + 4);
        }

        const float* Af = &As[cur][0][0];
        const float* Bf = &Bs[cur][0][0];
        #pragma unroll
        for (int ks = 0; ks < 4; ++ks) {
            const float2 fa = *(const float2*)&Af[4 * ks * LRA + baseA];
            const float4 fb = *(const float4*)&Bf[4 * ks * LRB + baseB];
            const double fa0 = fa.x, fa1 = fa.y;
            const double fb0 = fb.x, fb1 = fb.y, fb2 = fb.z, fb3 = fb.w;
#define MM(ti, ui, av, bv) \
            acc[ti][ui] = __builtin_amdgcn_mfma_f64_16x16x4f64(av, bv, acc[ti][ui], 0, 0, 0);
            MM(0,0,fa0,fb0) MM(0,1,fa0,fb1) MM(0,2,fa0,fb2) MM(0,3,fa0,fb3)
            MM(1,0,fa1,fb0) MM(1,1,fa1,fb1) MM(1,2,fa1,fb2) MM(1,3,fa1,fb3)
#undef MM
        }

        if (more) STAGE(cur ^ 1, pa0, pb0, pb1);
        __syncthreads();
        cur ^= 1;
    }

    // ---------------- epilogue under winning D-layout (r7-verified) ----------------
    #pragma unroll
    for (int v = 0; v < 4; ++v) {
        const int r16 = (selD == 0) ? 4 * lq + v : (selD == 1) ? lf
                      : (selD == 2) ? lq + 4 * v : lf;
        const int c16 = (selD == 0) ? lf : (selD == 1) ? 4 * lq + v
                      : (selD == 2) ? lf : lq + 4 * v;
        #pragma unroll
        for (int t = 0; t < 2; ++t) {
            const int row = bm + wrow * 32 + 16 * t + r16;
            #pragma unroll
            for (int u = 0; u < 4; ++u) {
                const int col = bn + wcol * 64 + 16 * u + c16;
                H[(size_t)row * NDIM + col] = acc[t][u][v] + (double)bias[col];
            }
        }
    }
}

// ---------------- epilogue chain (unchanged, verified r1/r4/r6/r7/r8) ----------------
__global__ __launch_bounds__(256) void bn_partial(
    const double* __restrict__ H, double* __restrict__ psum, double* __restrict__ psq)
{
    constexpr int N = 2048, ROWS = 128;
    const int o  = blockIdx.x * 256 + threadIdx.x;
    const int t0 = blockIdx.y * ROWS;
    double s = 0.0, q = 0.0;
    for (int r = 0; r < ROWS; ++r) {
        double h = H[(size_t)(t0 + r) * N + o];
        s += h;
        q = fma(h, h, q);
    }
    psum[(size_t)blockIdx.y * N + o] = s;
    psq [(size_t)blockIdx.y * N + o] = q;
}

__global__ void bn_finalize(const double* __restrict__ psum, const double* __restrict__ psq,
                            double* __restrict__ meanv, double* __restrict__ varv)
{
    constexpr int N = 2048, CH = 32;
    const int o = blockIdx.x * blockDim.x + threadIdx.x;
    double s = 0.0, q = 0.0;
    for (int c = 0; c < CH; ++c) {
        s += psum[(size_t)c * N + o];
        q += psq [(size_t)c * N + o];
    }
    const double m = s / 4096.0;
    meanv[o] = m;
    varv[o]  = q / 4096.0 - m * m;
}

__global__ __launch_bounds__(256) void bn_lif(
    const double* __restrict__ H,
    const double* __restrict__ meanv, const double* __restrict__ varv,
    const float* __restrict__ gamma, const float* __restrict__ beta_bn,
    const float* __restrict__ mem_init,
    const float* __restrict__ lif_beta, const float* __restrict__ thr,
    float* __restrict__ out)
{
    constexpr int T = 64, F = 2048;
    const int gid = blockIdx.x * 256 + threadIdx.x;
    const int o = gid & (F - 1);
    const int b = gid >> 11;

    const double m      = meanv[o];
    const double invstd = 1.0 / sqrt(varv[o] + 1e-5);
    const double sc     = invstd * (double)gamma[o];
    const double sh     = (double)beta_bn[o];
    const double beta_c = fmin(fmax((double)lif_beta[0], 0.0), 1.0);
    const double th     = (double)thr[0];

    double mem = (double)mem_init[gid];
    const double* hp = H   + (size_t)b * T * F + o;
    float*        op = out + (size_t)b * T * F + o;

    for (int t = 0; t < T; ++t) {
        const double h  = hp[(size_t)t * F];
        const double xt = (h - m) * sc + sh;
        const double reset = (mem > th) ? th : 0.0;
        mem = fma(beta_c, mem, xt) - reset;
        op[(size_t)t * F] = (mem > th) ? 1.0f : 0.0f;
    }
}

extern "C" void kernel_launch(void* const* d_in, const int* in_sizes, int n_in,
                              void* d_out, int out_size, void* d_ws, size_t ws_size,
                              hipStream_t stream)
{
    const float* x        = (const float*)d_in[0];
    const float* mem_init = (const float*)d_in[1];
    const float* W        = (const float*)d_in[2];
    const float* b        = (const float*)d_in[3];
    const float* gamma    = (const float*)d_in[4];
    const float* beta_bn  = (const float*)d_in[5];
    const float* lif_beta = (const float*)d_in[6];
    const float* thr      = (const float*)d_in[7];
    float* out = (float*)d_out;

    char* ws = (char*)d_ws;
    double* H     = (double*)ws;                                  // 64 MiB
    double* psum  = (double*)(ws + (size_t)67108864);
    double* psq   = (double*)(ws + (size_t)67108864 + 524288);
    double* meanv = (double*)(ws + (size_t)67108864 + 2 * 524288);
    double* varv  = meanv + 2048;

    gemm_f64_mfma4<<<dim3(64, 16), 256, 0, stream>>>(x, W, b, H);
    bn_partial    <<<dim3(8, 32),  256, 0, stream>>>(H, psum, psq);
    bn_finalize   <<<8,            256, 0, stream>>>(psum, psq, meanv, varv);
    bn_lif        <<<512,          256, 0, stream>>>(H, meanv, varv, gamma, beta_bn,
                                                     mem_init, lif_beta, thr, out);
}